// Round 15
// baseline (205.280 us; speedup 1.0000x reference)
//
#include <hip/hip_runtime.h>
#include <math.h>
#include <stdint.h>

typedef unsigned short u16;
typedef __attribute__((ext_vector_type(8))) short bf16x8;
typedef __attribute__((ext_vector_type(4))) float f32x4;

#define SEQ 2048
#define HIDN 2048
#define QLR 1536
#define NHEAD 16
#define DHEAD 192
#define DVAL 128
#define KLR 512
#define NCAT 2112  // QLR + (KLR + 64) fused qa|kva output width

__device__ __forceinline__ u16 f2bf(float f) {
  union { float f; uint32_t u; } v; v.f = f;
  uint32_t r = v.u + 0x7fffu + ((v.u >> 16) & 1u);
  return (u16)(r >> 16);
}
__device__ __forceinline__ float bf2f(u16 x) {
  union { uint32_t u; float f; } v; v.u = ((uint32_t)x) << 16;
  return v.f;
}

__device__ __forceinline__ void conv_span(const float* __restrict__ s, u16* __restrict__ d,
                                          int n4, int start, int stride) {
  for (int i = start; i < n4; i += stride) {
    float4 v = reinterpret_cast<const float4*>(s)[i];
    ushort4 o;
    o.x = f2bf(v.x); o.y = f2bf(v.y); o.z = f2bf(v.z); o.w = f2bf(v.w);
    reinterpret_cast<ushort4*>(d)[i] = o;
  }
}

// ---------------- conv stage 1: w_qa, w_kva (hidden handled in-GEMM) --------
__global__ __launch_bounds__(256) void convert2(
    const float* __restrict__ s0, u16* __restrict__ d0, int n0,
    const float* __restrict__ s1, u16* __restrict__ d1, int n1) {
  const float* s; u16* d; int n4;
  if (blockIdx.y == 0) { s = s0; d = d0; n4 = n0; }
  else                 { s = s1; d = d1; n4 = n1; }
  conv_span(s, d, n4, blockIdx.x * blockDim.x + threadIdx.x, gridDim.x * blockDim.x);
}

// ---------------- NT GEMM 128x128 (round-7 proven; kvb only) ----------------
template<bool BF16_OUT>
__global__ __launch_bounds__(256) void gemm_bt(const u16* __restrict__ A,
                                               const u16* __restrict__ B,
                                               void* __restrict__ Cv,
                                               int M, int N, int K) {
  __shared__ __align__(16) u16 As[2][128 * 64];
  __shared__ __align__(16) u16 Bs[2][128 * 64];
  const int tid = threadIdx.x;
  const int wid = tid >> 6;
  const int lane = tid & 63;
  const int lr = lane & 15;
  const int lh = lane >> 4;
  const int wm = wid >> 1, wn = wid & 1;
  const int rowBase = blockIdx.y * 128;
  const int colBase = blockIdx.x * 128;

  f32x4 acc[4][4] = {};

  auto stage = [&](int kt, int buf) {
#pragma unroll
    for (int c = 0; c < 4; ++c) {
      const int chunk = wid * 4 + c;
      const int slin = chunk * 64 + lane;
      const int row = slin >> 3;
      const int ks = slin & 7;
      const int kcol = kt * 64 + ((ks ^ (row & 7)) << 3);
      const u16* srcA = A + (size_t)(rowBase + row) * K + kcol;
      __builtin_amdgcn_global_load_lds((const __attribute__((address_space(1))) void*)srcA,
                                       (__attribute__((address_space(3))) void*)(&As[buf][0] + chunk * 512),
                                       16, 0, 0);
      const int brow = (colBase + row < N) ? (colBase + row) : (N - 1);
      const u16* srcB = B + (size_t)brow * K + kcol;
      __builtin_amdgcn_global_load_lds((const __attribute__((address_space(1))) void*)srcB,
                                       (__attribute__((address_space(3))) void*)(&Bs[buf][0] + chunk * 512),
                                       16, 0, 0);
    }
  };

  const int nkt = K >> 6;
  stage(0, 0);
  asm volatile("s_waitcnt vmcnt(0)" ::: "memory");
  __syncthreads();

  int cur = 0;
  for (int kt = 0; kt < nkt; ++kt) {
    if (kt + 1 < nkt) stage(kt + 1, cur ^ 1);
#pragma unroll
    for (int kk = 0; kk < 2; ++kk) {
      bf16x8 af[4], bfr[4];
#pragma unroll
      for (int m = 0; m < 4; ++m) {
        int row = wm * 64 + m * 16 + lr;
        int slot = (kk * 4 + lh) ^ (row & 7);
        af[m] = *reinterpret_cast<const bf16x8*>(&As[cur][0] + row * 64 + slot * 8);
      }
#pragma unroll
      for (int n = 0; n < 4; ++n) {
        int row = wn * 64 + n * 16 + lr;
        int slot = (kk * 4 + lh) ^ (row & 7);
        bfr[n] = *reinterpret_cast<const bf16x8*>(&Bs[cur][0] + row * 64 + slot * 8);
      }
#pragma unroll
      for (int m = 0; m < 4; ++m)
#pragma unroll
        for (int n = 0; n < 4; ++n)
          acc[m][n] = __builtin_amdgcn_mfma_f32_16x16x32_bf16(af[m], bfr[n], acc[m][n], 0, 0, 0);
    }
    asm volatile("s_waitcnt vmcnt(0)" ::: "memory");
    __syncthreads();
    cur ^= 1;
  }
#pragma unroll
  for (int m = 0; m < 4; ++m) {
#pragma unroll
    for (int n = 0; n < 4; ++n) {
#pragma unroll
      for (int j = 0; j < 4; ++j) {
        int row = rowBase + wm * 64 + m * 16 + lh * 4 + j;
        int col = colBase + wn * 64 + n * 16 + lr;
        if (col < N) {
          if (BF16_OUT)
            ((u16*)Cv)[(size_t)row * N + col] = f2bf(acc[m][n][j]);
          else
            ((float*)Cv)[(size_t)row * N + col] = acc[m][n][j];
        }
      }
    }
  }
}

// ---------------- NT GEMM core, 64x128 tile (48 KB LDS -> 3 blocks/CU) ------
template<bool BF16_OUT>
__device__ __forceinline__ void gemm_core64(u16* __restrict__ As, u16* __restrict__ Bs,
                                            const u16* __restrict__ A, const u16* __restrict__ B,
                                            void* __restrict__ Cv, int N, int K,
                                            int rowBase, int colBase) {
  const int tid = threadIdx.x;
  const int wid = tid >> 6;
  const int lane = tid & 63;
  const int lr = lane & 15;
  const int lh = lane >> 4;
  const int wm = wid >> 1, wn = wid & 1;

  f32x4 acc[2][4] = {};

  auto stage = [&](int kt, int buf) {
#pragma unroll
    for (int c = 0; c < 2; ++c) {
      const int slin = c * 256 + tid;
      const int row = slin >> 3;
      const int ks = slin & 7;
      const int kcol = kt * 64 + ((ks ^ (row & 7)) << 3);
      const u16* srcA = A + (size_t)(rowBase + row) * K + kcol;
      __builtin_amdgcn_global_load_lds((const __attribute__((address_space(1))) void*)srcA,
                                       (__attribute__((address_space(3))) void*)(As + buf * 4096 + slin * 8),
                                       16, 0, 0);
    }
#pragma unroll
    for (int c = 0; c < 4; ++c) {
      const int slin = c * 256 + tid;
      const int row = slin >> 3;
      const int ks = slin & 7;
      const int kcol = kt * 64 + ((ks ^ (row & 7)) << 3);
      const int brow = (colBase + row < N) ? (colBase + row) : (N - 1);
      const u16* srcB = B + (size_t)brow * K + kcol;
      __builtin_amdgcn_global_load_lds((const __attribute__((address_space(1))) void*)srcB,
                                       (__attribute__((address_space(3))) void*)(Bs + buf * 8192 + slin * 8),
                                       16, 0, 0);
    }
  };

  const int nkt = K >> 6;
  stage(0, 0);
  asm volatile("s_waitcnt vmcnt(0)" ::: "memory");
  __syncthreads();

  int cur = 0;
  for (int kt = 0; kt < nkt; ++kt) {
    if (kt + 1 < nkt) stage(kt + 1, cur ^ 1);
#pragma unroll
    for (int kk = 0; kk < 2; ++kk) {
      bf16x8 af[2], bfr[4];
#pragma unroll
      for (int m = 0; m < 2; ++m) {
        int row = wm * 32 + m * 16 + lr;
        int slot = (kk * 4 + lh) ^ (row & 7);
        af[m] = *reinterpret_cast<const bf16x8*>(As + cur * 4096 + row * 64 + slot * 8);
      }
#pragma unroll
      for (int n = 0; n < 4; ++n) {
        int row = wn * 64 + n * 16 + lr;
        int slot = (kk * 4 + lh) ^ (row & 7);
        bfr[n] = *reinterpret_cast<const bf16x8*>(Bs + cur * 8192 + row * 64 + slot * 8);
      }
#pragma unroll
      for (int m = 0; m < 2; ++m)
#pragma unroll
        for (int n = 0; n < 4; ++n)
          acc[m][n] = __builtin_amdgcn_mfma_f32_16x16x32_bf16(af[m], bfr[n], acc[m][n], 0, 0, 0);
    }
    asm volatile("s_waitcnt vmcnt(0)" ::: "memory");
    __syncthreads();
    cur ^= 1;
  }
#pragma unroll
  for (int m = 0; m < 2; ++m) {
#pragma unroll
    for (int n = 0; n < 4; ++n) {
#pragma unroll
      for (int j = 0; j < 4; ++j) {
        int row = rowBase + wm * 32 + m * 16 + lh * 4 + j;
        int col = colBase + wn * 64 + n * 16 + lr;
        if (col < N) {
          if (BF16_OUT)
            ((u16*)Cv)[(size_t)row * N + col] = f2bf(acc[m][n][j]);
          else
            ((float*)Cv)[(size_t)row * N + col] = acc[m][n][j];
        }
      }
    }
  }
}

// o-proj: 64x128 tiles, grid (16,32)=512 blocks -> 2/CU resident.
__global__ __launch_bounds__(256) void gemm_bt64_f32(const u16* __restrict__ A,
                                                     const u16* __restrict__ B,
                                                     float* __restrict__ C,
                                                     int N, int K) {
  __shared__ __align__(16) u16 As[2 * 4096];
  __shared__ __align__(16) u16 Bs[2 * 8192];
  gemm_core64<false>(As, Bs, A, B, C, N, K, blockIdx.y * 64, blockIdx.x * 128);
}

// qb: 64x128 tiles, grid (24,32)=768 blocks -> exact 3/CU capacity fit.
__global__ __launch_bounds__(256) void gemm_bt64_bf16(const u16* __restrict__ A,
                                                      const u16* __restrict__ B,
                                                      u16* __restrict__ C,
                                                      int N, int K) {
  __shared__ __align__(16) u16 As[2 * 4096];
  __shared__ __align__(16) u16 Bs[2 * 8192];
  gemm_core64<true>(As, Bs, A, B, C, N, K, blockIdx.y * 64, blockIdx.x * 128);
}

// ---------------- qa|kva GEMM with f32 A (in-staging conversion, T14) -------
// A = hidden (f32, K=2048). Per K-step: issue A f32 loads -> regs + B
// global_load_lds; compute(cur); vmcnt(0); convert+ds_write A; barrier.
// Numerics identical to pre-converted path (same f2bf RNE).
// Blocks 0..543: GEMM; 544..735: grid-stride conv of w_qb / w_kvb / w_o.
__global__ __launch_bounds__(256) void gemm_qakva_conv(
    const float* __restrict__ hidden, const u16* __restrict__ wcat, u16* __restrict__ qpre,
    const float* __restrict__ s0, u16* __restrict__ d0, int n0,
    const float* __restrict__ s1, u16* __restrict__ d1, int n1,
    const float* __restrict__ s2, u16* __restrict__ d2, int n2) {
  __shared__ __align__(16) u16 As[2 * 4096];
  __shared__ __align__(16) u16 Bs[2 * 8192];
  const int bx = blockIdx.x;
  if (bx >= 544) {
    const int t = bx - 544;
    const int seg = t >> 6, lb = t & 63;
    const float* s; u16* d; int n4;
    if (seg == 0)      { s = s0; d = d0; n4 = n0; }
    else if (seg == 1) { s = s1; d = d1; n4 = n1; }
    else               { s = s2; d = d2; n4 = n2; }
    conv_span(s, d, n4, lb * 256 + threadIdx.x, 64 * 256);
    return;
  }
  const int rowBase = (bx / 17) * 64;
  const int colBase = (bx % 17) * 128;
  const int N = NCAT, K = HIDN;
  const int tid = threadIdx.x;
  const int wid = tid >> 6;
  const int lane = tid & 63;
  const int lr = lane & 15;
  const int lh = lane >> 4;
  const int wm = wid >> 1, wn = wid & 1;

  f32x4 acc[2][4] = {};

  // A addressing (invariant parts)
  int aRow[2], aOff[2];
#pragma unroll
  for (int c = 0; c < 2; ++c) {
    const int slin = c * 256 + tid;
    aRow[c] = slin >> 3;
    const int ks = slin & 7;
    aOff[c] = (ks ^ (aRow[c] & 7)) << 3;  // swizzled 8-elem column within K-step
  }

  float4 rA[2][2];
  auto issueA = [&](int kt) {
#pragma unroll
    for (int c = 0; c < 2; ++c) {
      const float* src = hidden + (size_t)(rowBase + aRow[c]) * K + kt * 64 + aOff[c];
      rA[c][0] = reinterpret_cast<const float4*>(src)[0];
      rA[c][1] = reinterpret_cast<const float4*>(src)[1];
    }
  };
  auto writeA = [&](int buf) {
#pragma unroll
    for (int c = 0; c < 2; ++c) {
      const int slin = c * 256 + tid;
      bf16x8 o;
      o[0] = (short)f2bf(rA[c][0].x); o[1] = (short)f2bf(rA[c][0].y);
      o[2] = (short)f2bf(rA[c][0].z); o[3] = (short)f2bf(rA[c][0].w);
      o[4] = (short)f2bf(rA[c][1].x); o[5] = (short)f2bf(rA[c][1].y);
      o[6] = (short)f2bf(rA[c][1].z); o[7] = (short)f2bf(rA[c][1].w);
      *reinterpret_cast<bf16x8*>(As + buf * 4096 + slin * 8) = o;
    }
  };
  auto issueB = [&](int kt, int buf) {
#pragma unroll
    for (int c = 0; c < 4; ++c) {
      const int slin = c * 256 + tid;
      const int row = slin >> 3;
      const int ks = slin & 7;
      const int kcol = kt * 64 + ((ks ^ (row & 7)) << 3);
      const int brow = (colBase + row < N) ? (colBase + row) : (N - 1);
      const u16* srcB = wcat + (size_t)brow * K + kcol;
      __builtin_amdgcn_global_load_lds((const __attribute__((address_space(1))) void*)srcB,
                                       (__attribute__((address_space(3))) void*)(Bs + buf * 8192 + slin * 8),
                                       16, 0, 0);
    }
  };

  const int nkt = K >> 6;
  issueA(0);
  issueB(0, 0);
  asm volatile("s_waitcnt vmcnt(0)" ::: "memory");
  writeA(0);
  __syncthreads();

  int cur = 0;
  for (int kt = 0; kt < nkt; ++kt) {
    const bool more = (kt + 1 < nkt);
    if (more) { issueA(kt + 1); issueB(kt + 1, cur ^ 1); }
#pragma unroll
    for (int kk = 0; kk < 2; ++kk) {
      bf16x8 af[2], bfr[4];
#pragma unroll
      for (int m = 0; m < 2; ++m) {
        int row = wm * 32 + m * 16 + lr;
        int slot = (kk * 4 + lh) ^ (row & 7);
        af[m] = *reinterpret_cast<const bf16x8*>(As + cur * 4096 + row * 64 + slot * 8);
      }
#pragma unroll
      for (int n = 0; n < 4; ++n) {
        int row = wn * 64 + n * 16 + lr;
        int slot = (kk * 4 + lh) ^ (row & 7);
        bfr[n] = *reinterpret_cast<const bf16x8*>(Bs + cur * 8192 + row * 64 + slot * 8);
      }
#pragma unroll
      for (int m = 0; m < 2; ++m)
#pragma unroll
        for (int n = 0; n < 4; ++n)
          acc[m][n] = __builtin_amdgcn_mfma_f32_16x16x32_bf16(af[m], bfr[n], acc[m][n], 0, 0, 0);
    }
    asm volatile("s_waitcnt vmcnt(0)" ::: "memory");
    if (more) writeA(cur ^ 1);
    __syncthreads();
    cur ^= 1;
  }
#pragma unroll
  for (int m = 0; m < 2; ++m) {
#pragma unroll
    for (int n = 0; n < 4; ++n) {
#pragma unroll
      for (int j = 0; j < 4; ++j) {
        int row = rowBase + wm * 32 + m * 16 + lh * 4 + j;
        int col = colBase + wn * 64 + n * 16 + lr;
        if (col < N)
          qpre[(size_t)row * N + col] = f2bf(acc[m][n][j]);
      }
    }
  }
}

// ---------------- fused RMSNorm (q-latent & k-latent) -----------------------
__global__ __launch_bounds__(256) void rmsnorm2_kernel(const u16* __restrict__ qpre,
                                                       const float* __restrict__ wq,
                                                       u16* __restrict__ qlat,
                                                       const float* __restrict__ wk,
                                                       u16* __restrict__ klat) {
  const int row = blockIdx.x;
  const u16* x; u16* o; const float* w; int L;
  if (blockIdx.y == 0) { x = qpre + (size_t)row * NCAT;       w = wq; o = qlat + (size_t)row * QLR; L = QLR; }
  else                 { x = qpre + (size_t)row * NCAT + QLR; w = wk; o = klat + (size_t)row * KLR; L = KLR; }
  int tid = threadIdx.x;
  float ss = 0.f;
  for (int i = tid; i < L; i += 256) { float v = bf2f(x[i]); ss += v * v; }
#pragma unroll
  for (int off = 32; off > 0; off >>= 1) ss += __shfl_down(ss, off);
  __shared__ float red[4];
  if ((tid & 63) == 0) red[tid >> 6] = ss;
  __syncthreads();
  float tot = red[0] + red[1] + red[2] + red[3];
  float sc = rsqrtf(tot / (float)L + 1e-6f);
  for (int i = tid; i < L; i += 256) o[i] = f2bf(bf2f(x[i]) * sc * w[i]);
}

// ---------------- fused prep: rope(q) | build_k | vtrans --------------------
__global__ __launch_bounds__(256) void prep_kernel(u16* __restrict__ qbuf,
                                                   const u16* __restrict__ kvbuf,
                                                   const u16* __restrict__ qpre,
                                                   const float* __restrict__ cosb,
                                                   const float* __restrict__ sinb,
                                                   u16* __restrict__ Kf,
                                                   u16* __restrict__ Vt) {
  __shared__ u16 sh[32 * 33];
  const int bx = blockIdx.x;
  const int tid = threadIdx.x;
  if (bx < 128) {
    int t = bx * 256 + tid;
    int s = t >> 4, h = t & 15;
    u16* x = qbuf + (size_t)s * (NHEAD * DHEAD) + h * DHEAD + 128;
    float xv[64];
#pragma unroll
    for (int i = 0; i < 64; ++i) xv[i] = bf2f(x[i]);
#pragma unroll
    for (int i = 0; i < 32; ++i) {
      float c = cosb[s * 64 + i], sn = sinb[s * 64 + i];
      x[i]      = f2bf(xv[2 * i] * c - xv[2 * i + 1] * sn);
      x[32 + i] = f2bf(xv[2 * i + 1] * c + xv[2 * i] * sn);
    }
  } else if (bx < 128 + 2048) {
    int s = bx - 128;
    u16* krot = sh;
    if (tid < 32) {
      float c = cosb[s * 64 + tid], sn = sinb[s * 64 + tid];
      float x0 = bf2f(qpre[(size_t)s * NCAT + 2048 + 2 * tid]);
      float x1 = bf2f(qpre[(size_t)s * NCAT + 2048 + 2 * tid + 1]);
      krot[tid]      = f2bf(x0 * c - x1 * sn);
      krot[32 + tid] = f2bf(x1 * c + x0 * sn);
    }
    __syncthreads();
    for (int idx = tid; idx < NHEAD * DHEAD; idx += 256) {
      int h = idx / DHEAD, d = idx % DHEAD;
      u16 v = (d < 128) ? kvbuf[(size_t)s * 4096 + h * 256 + d] : krot[d - 128];
      Kf[((size_t)h * SEQ + s) * DHEAD + d] = v;
    }
  } else {
    int t = bx - 2176;
    int st = t & 63, dt = (t >> 6) & 3, h = t >> 8;
    u16 (*tile)[33] = (u16 (*)[33])sh;
    int tx = tid & 31, ty = tid >> 5;
#pragma unroll
    for (int i = 0; i < 4; ++i) {
      int ss = st * 32 + ty + i * 8;
      tile[ty + i * 8][tx] = kvbuf[(size_t)ss * 4096 + h * 256 + 128 + dt * 32 + tx];
    }
    __syncthreads();
#pragma unroll
    for (int i = 0; i < 4; ++i) {
      int d = dt * 32 + ty + i * 8;
      Vt[((size_t)h * DVAL + d) * SEQ + st * 32 + tx] = tile[tx][ty + i * 8];
    }
  }
}

// ---------------- Causal flash attention, 2-way split-K (R11 pipeline) ------
// + T13 defer-max (THR=8).
__global__ __launch_bounds__(256, 3) void attn_kernel(const u16* __restrict__ qbuf,
                                                      const u16* __restrict__ Kf,
                                                      const u16* __restrict__ Vt,
                                                      u16* __restrict__ attn_out,
                                                      float* __restrict__ Opart,
                                                      float* __restrict__ mlp,
                                                      float scaling) {
  const int bx = blockIdx.x;
  int h, qt, chunk;
  if (bx < 256)      { h = bx & 15;          qt = 31 - (bx >> 4);        chunk = 0; }
  else if (bx < 512) { int t = bx - 256; h = t & 15; qt = t >> 4;        chunk = 0; }
  else               { int t = bx - 512; h = t & 15; qt = 31 - (t >> 4); chunk = 1; }
  const int kt0 = chunk ? 16 : 0;
  const int kte = chunk ? qt : (qt < 15 ? qt : 15);
  const bool direct = (qt < 16);

  const int tid = threadIdx.x;
  const int wid = tid >> 6;
  const int lane = tid & 63;
  const int lr = lane & 15, lh = lane >> 4;

  __shared__ __align__(16) u16 Kl[64 * 192];
  __shared__ __align__(16) u16 Vl[144 * 64];
  __shared__ __align__(16) u16 Plds[4 * 1024];
  u16* Pw = Plds + wid * 1024;
  const int q0 = qt * 64 + wid * 16;

  for (int i = tid; i < 16 * 64; i += 256) Vl[128 * 64 + i] = 0x3F80;

  bf16x8 qf[6];
#pragma unroll
  for (int c = 0; c < 6; ++c) {
    bf16x8 q = *reinterpret_cast<const bf16x8*>(qbuf + (size_t)(q0 + lr) * (NHEAD * DHEAD) +
                                                h * DHEAD + c * 32 + lh * 8);
    bf16x8 o;
#pragma unroll
    for (int e = 0; e < 8; ++e) o[e] = (short)f2bf(bf2f((u16)q[e]) * scaling);
    qf[c] = o;
  }

  int kSrc[6], kDst[6];
#pragma unroll
  for (int i = 0; i < 6; ++i) {
    int slin = i * 256 + tid;
    int row = slin / 24;
    int ck = slin - row * 24;
    int srcck = (ck & 0x18) | ((ck & 7) ^ (row & 7));
    kSrc[i] = row * DHEAD + srcck * 8;
    kDst[i] = slin * 8;
  }
  int vSrc[4], vDst[4];
#pragma unroll
  for (int i = 0; i < 4; ++i) {
    int slin = i * 256 + tid;
    int d = slin >> 3, c = slin & 7;
    vSrc[i] = (c ^ (d & 7)) * 8;
    vDst[i] = slin * 8;
  }
  int qkOff[4][6];
#pragma unroll
  for (int f = 0; f < 4; ++f)
#pragma unroll
    for (int c = 0; c < 6; ++c) {
      int row = f * 16 + lr;
      int ckg = c * 4 + lh;
      int ck = (ckg & 0x18) | ((ckg & 7) ^ (row & 7));
      qkOff[f][c] = row * DHEAD + ck * 8;
    }
  int pvOff[9][2];
#pragma unroll
  for (int f = 0; f < 9; ++f)
#pragma unroll
    for (int kk = 0; kk < 2; ++kk) {
      int d = f * 16 + lr;
      int ckg = kk * 4 + lh;
      pvOff[f][kk] = d * 64 + ((ckg ^ (d & 7)) * 8);
    }
  int paOff[2];
#pragma unroll
  for (int kk = 0; kk < 2; ++kk) paOff[kk] = lr * 64 + (((kk * 4 + lh) ^ (lr & 7)) * 8);
  int pIdx[4][4];
#pragma unroll
  for (int f = 0; f < 4; ++f)
#pragma unroll
    for (int j = 0; j < 4; ++j) {
      int rp = lh * 4 + j;
      int col = f * 16 + lr;
      pIdx[f][j] = rp * 64 + (((col >> 3) ^ (rp & 7)) << 3) + (col & 7);
    }

  auto stageK = [&](int kt) {
    const u16* base = Kf + ((size_t)h * SEQ + kt * 64) * DHEAD;
#pragma unroll
    for (int i = 0; i < 6; ++i)
      __builtin_amdgcn_global_load_lds(
          (const __attribute__((address_space(1))) void*)(base + kSrc[i]),
          (__attribute__((address_space(3))) void*)(Kl + kDst[i]), 16, 0, 0);
  };
  auto stageV = [&](int kt) {
    const u16* base = Vt + (size_t)h * DVAL * SEQ + kt * 64;
#pragma unroll
    for (int i = 0; i < 4; ++i) {
      int d = (i * 256 + tid) >> 3;
      __builtin_amdgcn_global_load_lds(
          (const __attribute__((address_space(1))) void*)(base + (size_t)d * SEQ + vSrc[i]),
          (__attribute__((address_space(3))) void*)(Vl + vDst[i]), 16, 0, 0);
    }
  };

  float m_j[4];
  f32x4 acc[9] = {};
#pragma unroll
  for (int j = 0; j < 4; ++j) m_j[j] = -1e30f;

  stageK(kt0);
  asm volatile("s_waitcnt vmcnt(0)" ::: "memory");
  __syncthreads();

  auto do_iter = [&](int kt, bool maskTile, bool hasNextK) {
    stageV(kt);

    asm volatile("s_waitcnt vmcnt(4)" ::: "memory");
    __builtin_amdgcn_s_barrier();

    f32x4 sf[4] = {};
    __builtin_amdgcn_s_setprio(1);
#pragma unroll
    for (int f = 0; f < 4; ++f)
#pragma unroll
      for (int c = 0; c < 6; ++c) {
        bf16x8 kf = *reinterpret_cast<const bf16x8*>(Kl + qkOff[f][c]);
        sf[f] = __builtin_amdgcn_mfma_f32_16x16x32_bf16(qf[c], kf, sf[f], 0, 0, 0);
      }
    __builtin_amdgcn_s_setprio(0);

    __builtin_amdgcn_s_barrier();
    if (hasNextK) stageK(kt + 1);

    float mx[4];
#pragma unroll
    for (int j = 0; j < 4; ++j) mx[j] = -1e30f;
#pragma unroll
    for (int f = 0; f < 4; ++f)
#pragma unroll
      for (int j = 0; j < 4; ++j) {
        float v = sf[f][j];
        if (maskTile) {
          int kcol = kt * 64 + f * 16 + lr;
          int qrow = q0 + lh * 4 + j;
          if (kcol > qrow) v = -1e30f;
          sf[f][j] = v;
        }
        mx[j] = fmaxf(mx[j], v);
      }
#pragma unroll
    for (int off = 1; off < 16; off <<= 1)
#pragma unroll
      for (int j = 0; j < 4; ++j) mx[j] = fmaxf(mx[j], __shfl_xor(mx[j], off));

    bool need = false;
#pragma unroll
    for (int j = 0; j < 4; ++j) need |= (mx[j] > m_j[j] + 8.0f);
    if (__any(need)) {
      float al[4];
#pragma unroll
      for (int j = 0; j < 4; ++j) {
        float mn = fmaxf(m_j[j], mx[j]);
        al[j] = __expf(m_j[j] - mn);
        m_j[j] = mn;
      }
#pragma unroll
      for (int f = 0; f < 9; ++f)
#pragma unroll
        for (int j = 0; j < 4; ++j) acc[f][j] *= al[j];
    }
#pragma unroll
    for (int f = 0; f < 4; ++f)
#pragma unroll
      for (int j = 0; j < 4; ++j) {
        float p = __expf(sf[f][j] - m_j[j]);
        Pw[pIdx[f][j]] = f2bf(p);
      }

    if (hasNextK) asm volatile("s_waitcnt vmcnt(6)" ::: "memory");
    else          asm volatile("s_waitcnt vmcnt(0)" ::: "memory");
    __builtin_amdgcn_s_barrier();

    __builtin_amdgcn_s_setprio(1);
#pragma unroll
    for (int kk = 0; kk < 2; ++kk) {
      bf16x8 pa = *reinterpret_cast<const bf16x8*>(Pw + paOff[kk]);
#pragma unroll
      for (int f = 0; f < 9; ++f) {
        bf16x8 vb = *reinterpret_cast<const bf16x8*>(Vl + pvOff[f][kk]);
        acc[f] = __builtin_amdgcn_mfma_f32_16x16x32_bf16(pa, vb, acc[f], 0, 0, 0);
      }
    }
    __builtin_amdgcn_s_setprio(0);

    if (hasNextK) __builtin_amdgcn_s_barrier();
  };

  for (int kt = kt0; kt < kte; ++kt) do_iter(kt, false, true);
  do_iter(kte, kte == qt, false);

  if (direct) {
#pragma unroll
    for (int f = 0; f < 8; ++f)
#pragma unroll
      for (int j = 0; j < 4; ++j) {
        int row = q0 + lh * 4 + j;
        float l = acc[8][j];
        attn_out[(size_t)row * (NHEAD * DVAL) + h * DVAL + f * 16 + lr] = f2bf(acc[f][j] / l);
      }
  } else {
    const int pidx = h * 16 + (qt - 16);
    float* Op = Opart + (size_t)(pidx * 2 + chunk) * 8192;
#pragma unroll
    for (int f = 0; f < 8; ++f)
#pragma unroll
      for (int j = 0; j < 4; ++j) {
        int r = wid * 16 + lh * 4 + j;
        Op[r * 128 + f * 16 + lr] = acc[f][j];
      }
    if (lr == 0) {
      float* mlb = mlp + (pidx * 2 + chunk) * 128;
#pragma unroll
      for (int j = 0; j < 4; ++j) {
        int r = wid * 16 + lh * 4 + j;
        mlb[r] = m_j[j];
        mlb[64 + r] = acc[8][j];
      }
    }
  }
}

// ---------------- combine two split-K partials (512 blocks, half each) ------
__global__ __launch_bounds__(256) void attn_combine(const float* __restrict__ Opart,
                                                    const float* __restrict__ mlp,
                                                    u16* __restrict__ attnb) {
  const int b = blockIdx.x;
  const int pid = b >> 1, half = b & 1;
  const int h = pid & 15, q2 = pid >> 4;
  const int pidx = h * 16 + q2;
  const int qt = 16 + q2;
  const float* O0 = Opart + (size_t)(pidx * 2 + 0) * 8192;
  const float* O1 = Opart + (size_t)(pidx * 2 + 1) * 8192;
  const float* ml0 = mlp + (pidx * 2 + 0) * 128;
  const float* ml1 = mlp + (pidx * 2 + 1) * 128;
  __shared__ float w0s[64], w1s[64], iLs[64];
  const int tid = threadIdx.x;
  if (tid < 64) {
    float m0 = ml0[tid], l0 = ml0[64 + tid];
    float m1 = ml1[tid], l1 = ml1[64 + tid];
    float M = fmaxf(m0, m1);
    float a0 = __expf(m0 - M), a1 = __expf(m1 - M);
    w0s[tid] = a0; w1s[tid] = a1;
    iLs[tid] = 1.f / (l0 * a0 + l1 * a1);
  }
  __syncthreads();
  const int base = half * 4096, end = base + 4096;
  for (int idx = base + tid; idx < end; idx += 256) {
    int r = idx >> 7, c = idx & 127;
    float o = (O0[idx] * w0s[r] + O1[idx] * w1s[r]) * iLs[r];
    attnb[(size_t)(qt * 64 + r) * (NHEAD * DVAL) + h * DVAL + c] = f2bf(o);
  }
}

// ---------------- launch ----------------------------------------------------
extern "C" void kernel_launch(void* const* d_in, const int* in_sizes, int n_in,
                              void* d_out, int out_size, void* d_ws, size_t ws_size,
                              hipStream_t stream) {
  const float* hidden   = (const float*)d_in[0];
  const float* cosb     = (const float*)d_in[1];
  const float* sinb     = (const float*)d_in[2];
  const float* w_qa     = (const float*)d_in[3];
  const float* w_qa_ln  = (const float*)d_in[4];
  const float* w_qb     = (const float*)d_in[5];
  const float* w_kva    = (const float*)d_in[6];
  const float* w_kva_ln = (const float*)d_in[7];
  const float* w_kvb    = (const float*)d_in[8];
  const float* w_o      = (const float*)d_in[9];
  float* out = (float*)d_out;

  char* ws = (char*)d_ws;
  size_t off = 0;
  auto alloc = [&](size_t bytes) -> char* {
    char* p = ws + off;
    off = (off + bytes + 255) & ~(size_t)255;
    return p;
  };
  u16* wcat   = (u16*)alloc((size_t)NCAT * HIDN * 2);
  u16* wqbbf  = (u16*)alloc((size_t)(NHEAD * DHEAD) * QLR * 2);
  u16* wkvbbf = (u16*)alloc((size_t)4096 * KLR * 2);
  u16* qpre   = (u16*)alloc((size_t)SEQ * NCAT * 2);
  u16* qlat   = (u16*)alloc((size_t)SEQ * QLR * 2);
  u16* klat   = (u16*)alloc((size_t)SEQ * KLR * 2);
  u16* kvbuf  = (u16*)alloc((size_t)SEQ * 4096 * 2);
  u16* wobf   = (u16*)alloc((size_t)HIDN * HIDN * 2);
  u16* qbuf   = (u16*)alloc((size_t)SEQ * NHEAD * DHEAD * 2);
  u16* Kf     = (u16*)alloc((size_t)NHEAD * SEQ * DHEAD * 2);
  u16* Vt     = (u16*)alloc((size_t)NHEAD * DVAL * SEQ * 2);
  u16* attnb  = (u16*)alloc((size_t)SEQ * NHEAD * DVAL * 2);
  (void)ws_size; (void)n_in; (void)in_sizes; (void)out_size;

  // split-K partials alias the dead-by-attn region (wcat..kvbuf ~ 45 MB)
  float* Opart = (float*)ws;
  float* mlp   = (float*)(ws + (size_t)512 * 8192 * 4);

  convert2<<<dim3(512, 2), 256, 0, stream>>>(
      w_qa, wcat, QLR * HIDN / 4,
      w_kva, wcat + (size_t)QLR * HIDN, 576 * HIDN / 4);

  gemm_qakva_conv<<<dim3(736), 256, 0, stream>>>(
      hidden, wcat, qpre,
      w_qb, wqbbf, NHEAD * DHEAD * QLR / 4,
      w_kvb, wkvbbf, 4096 * KLR / 4,
      w_o, wobf, HIDN * HIDN / 4);

  rmsnorm2_kernel<<<dim3(SEQ, 2), 256, 0, stream>>>(qpre, w_qa_ln, qlat, w_kva_ln, klat);

  gemm_bt64_bf16<<<dim3((NHEAD * DHEAD) / 128, SEQ / 64), 256, 0, stream>>>(qlat, wqbbf, qbuf, NHEAD * DHEAD, QLR);
  gemm_bt<true><<<dim3(4096 / 128, SEQ / 128), 256, 0, stream>>>(klat, wkvbbf, kvbuf, SEQ, 4096, KLR);

  prep_kernel<<<dim3(6272), 256, 0, stream>>>(qbuf, kvbuf, qpre, cosb, sinb, Kf, Vt);

  double Mm = 0.1 * log(40.0) + 1.0;
  float scaling = (float)(pow((double)DHEAD, -0.5) * Mm * Mm);
  attn_kernel<<<dim3(768), 256, 0, stream>>>(qbuf, Kf, Vt, attnb, Opart, mlp, scaling);
  attn_combine<<<dim3(512), 256, 0, stream>>>(Opart, mlp, attnb);

  gemm_bt64_f32<<<dim3(HIDN / 128, SEQ / 64), 256, 0, stream>>>(attnb, wobf, out, HIDN, HIDN);
}

// Round 16
// 191.197 us; speedup vs baseline: 1.0737x; 1.0737x over previous
//
#include <hip/hip_runtime.h>
#include <math.h>
#include <stdint.h>

typedef unsigned short u16;
typedef __attribute__((ext_vector_type(8))) short bf16x8;
typedef __attribute__((ext_vector_type(4))) float f32x4;

#define SEQ 2048
#define HIDN 2048
#define QLR 1536
#define NHEAD 16
#define DHEAD 192
#define DVAL 128
#define KLR 512
#define NCAT 2112  // QLR + (KLR + 64) fused qa|kva output width

__device__ __forceinline__ u16 f2bf(float f) {
  union { float f; uint32_t u; } v; v.f = f;
  uint32_t r = v.u + 0x7fffu + ((v.u >> 16) & 1u);
  return (u16)(r >> 16);
}
__device__ __forceinline__ float bf2f(u16 x) {
  union { uint32_t u; float f; } v; v.u = ((uint32_t)x) << 16;
  return v.f;
}

__device__ __forceinline__ void conv_span(const float* __restrict__ s, u16* __restrict__ d,
                                          int n4, int start, int stride) {
  for (int i = start; i < n4; i += stride) {
    float4 v = reinterpret_cast<const float4*>(s)[i];
    ushort4 o;
    o.x = f2bf(v.x); o.y = f2bf(v.y); o.z = f2bf(v.z); o.w = f2bf(v.w);
    reinterpret_cast<ushort4*>(d)[i] = o;
  }
}

// ---------------- conv stage 1: hidden, w_qa, w_kva -------------------------
// R15 lesson: hidden must be PRE-converted (17x reuse across column tiles;
// in-GEMM f32 staging doubled HBM traffic -> 68us HBM-bound dispatch).
__global__ __launch_bounds__(256) void convert3(
    const float* __restrict__ s0, u16* __restrict__ d0, int n0,
    const float* __restrict__ s1, u16* __restrict__ d1, int n1,
    const float* __restrict__ s2, u16* __restrict__ d2, int n2) {
  const float* s; u16* d; int n4;
  switch (blockIdx.y) {
    case 0: s = s0; d = d0; n4 = n0; break;
    case 1: s = s1; d = d1; n4 = n1; break;
    default: s = s2; d = d2; n4 = n2; break;
  }
  conv_span(s, d, n4, blockIdx.x * blockDim.x + threadIdx.x, gridDim.x * blockDim.x);
}

// ---------------- NT GEMM 128x128 (round-7 proven; kvb only) ----------------
template<bool BF16_OUT>
__global__ __launch_bounds__(256) void gemm_bt(const u16* __restrict__ A,
                                               const u16* __restrict__ B,
                                               void* __restrict__ Cv,
                                               int M, int N, int K) {
  __shared__ __align__(16) u16 As[2][128 * 64];
  __shared__ __align__(16) u16 Bs[2][128 * 64];
  const int tid = threadIdx.x;
  const int wid = tid >> 6;
  const int lane = tid & 63;
  const int lr = lane & 15;
  const int lh = lane >> 4;
  const int wm = wid >> 1, wn = wid & 1;
  const int rowBase = blockIdx.y * 128;
  const int colBase = blockIdx.x * 128;

  f32x4 acc[4][4] = {};

  auto stage = [&](int kt, int buf) {
#pragma unroll
    for (int c = 0; c < 4; ++c) {
      const int chunk = wid * 4 + c;
      const int slin = chunk * 64 + lane;
      const int row = slin >> 3;
      const int ks = slin & 7;
      const int kcol = kt * 64 + ((ks ^ (row & 7)) << 3);
      const u16* srcA = A + (size_t)(rowBase + row) * K + kcol;
      __builtin_amdgcn_global_load_lds((const __attribute__((address_space(1))) void*)srcA,
                                       (__attribute__((address_space(3))) void*)(&As[buf][0] + chunk * 512),
                                       16, 0, 0);
      const int brow = (colBase + row < N) ? (colBase + row) : (N - 1);
      const u16* srcB = B + (size_t)brow * K + kcol;
      __builtin_amdgcn_global_load_lds((const __attribute__((address_space(1))) void*)srcB,
                                       (__attribute__((address_space(3))) void*)(&Bs[buf][0] + chunk * 512),
                                       16, 0, 0);
    }
  };

  const int nkt = K >> 6;
  stage(0, 0);
  asm volatile("s_waitcnt vmcnt(0)" ::: "memory");
  __syncthreads();

  int cur = 0;
  for (int kt = 0; kt < nkt; ++kt) {
    if (kt + 1 < nkt) stage(kt + 1, cur ^ 1);
#pragma unroll
    for (int kk = 0; kk < 2; ++kk) {
      bf16x8 af[4], bfr[4];
#pragma unroll
      for (int m = 0; m < 4; ++m) {
        int row = wm * 64 + m * 16 + lr;
        int slot = (kk * 4 + lh) ^ (row & 7);
        af[m] = *reinterpret_cast<const bf16x8*>(&As[cur][0] + row * 64 + slot * 8);
      }
#pragma unroll
      for (int n = 0; n < 4; ++n) {
        int row = wn * 64 + n * 16 + lr;
        int slot = (kk * 4 + lh) ^ (row & 7);
        bfr[n] = *reinterpret_cast<const bf16x8*>(&Bs[cur][0] + row * 64 + slot * 8);
      }
#pragma unroll
      for (int m = 0; m < 4; ++m)
#pragma unroll
        for (int n = 0; n < 4; ++n)
          acc[m][n] = __builtin_amdgcn_mfma_f32_16x16x32_bf16(af[m], bfr[n], acc[m][n], 0, 0, 0);
    }
    asm volatile("s_waitcnt vmcnt(0)" ::: "memory");
    __syncthreads();
    cur ^= 1;
  }
#pragma unroll
  for (int m = 0; m < 4; ++m) {
#pragma unroll
    for (int n = 0; n < 4; ++n) {
#pragma unroll
      for (int j = 0; j < 4; ++j) {
        int row = rowBase + wm * 64 + m * 16 + lh * 4 + j;
        int col = colBase + wn * 64 + n * 16 + lr;
        if (col < N) {
          if (BF16_OUT)
            ((u16*)Cv)[(size_t)row * N + col] = f2bf(acc[m][n][j]);
          else
            ((float*)Cv)[(size_t)row * N + col] = acc[m][n][j];
        }
      }
    }
  }
}

// ---------------- NT GEMM core, 64x128 tile (48 KB LDS -> 3 blocks/CU) ------
template<bool BF16_OUT>
__device__ __forceinline__ void gemm_core64(u16* __restrict__ As, u16* __restrict__ Bs,
                                            const u16* __restrict__ A, const u16* __restrict__ B,
                                            void* __restrict__ Cv, int N, int K,
                                            int rowBase, int colBase) {
  const int tid = threadIdx.x;
  const int wid = tid >> 6;
  const int lane = tid & 63;
  const int lr = lane & 15;
  const int lh = lane >> 4;
  const int wm = wid >> 1, wn = wid & 1;

  f32x4 acc[2][4] = {};

  auto stage = [&](int kt, int buf) {
#pragma unroll
    for (int c = 0; c < 2; ++c) {
      const int slin = c * 256 + tid;
      const int row = slin >> 3;
      const int ks = slin & 7;
      const int kcol = kt * 64 + ((ks ^ (row & 7)) << 3);
      const u16* srcA = A + (size_t)(rowBase + row) * K + kcol;
      __builtin_amdgcn_global_load_lds((const __attribute__((address_space(1))) void*)srcA,
                                       (__attribute__((address_space(3))) void*)(As + buf * 4096 + slin * 8),
                                       16, 0, 0);
    }
#pragma unroll
    for (int c = 0; c < 4; ++c) {
      const int slin = c * 256 + tid;
      const int row = slin >> 3;
      const int ks = slin & 7;
      const int kcol = kt * 64 + ((ks ^ (row & 7)) << 3);
      const int brow = (colBase + row < N) ? (colBase + row) : (N - 1);
      const u16* srcB = B + (size_t)brow * K + kcol;
      __builtin_amdgcn_global_load_lds((const __attribute__((address_space(1))) void*)srcB,
                                       (__attribute__((address_space(3))) void*)(Bs + buf * 8192 + slin * 8),
                                       16, 0, 0);
    }
  };

  const int nkt = K >> 6;
  stage(0, 0);
  asm volatile("s_waitcnt vmcnt(0)" ::: "memory");
  __syncthreads();

  int cur = 0;
  for (int kt = 0; kt < nkt; ++kt) {
    if (kt + 1 < nkt) stage(kt + 1, cur ^ 1);
#pragma unroll
    for (int kk = 0; kk < 2; ++kk) {
      bf16x8 af[2], bfr[4];
#pragma unroll
      for (int m = 0; m < 2; ++m) {
        int row = wm * 32 + m * 16 + lr;
        int slot = (kk * 4 + lh) ^ (row & 7);
        af[m] = *reinterpret_cast<const bf16x8*>(As + cur * 4096 + row * 64 + slot * 8);
      }
#pragma unroll
      for (int n = 0; n < 4; ++n) {
        int row = wn * 64 + n * 16 + lr;
        int slot = (kk * 4 + lh) ^ (row & 7);
        bfr[n] = *reinterpret_cast<const bf16x8*>(Bs + cur * 8192 + row * 64 + slot * 8);
      }
#pragma unroll
      for (int m = 0; m < 2; ++m)
#pragma unroll
        for (int n = 0; n < 4; ++n)
          acc[m][n] = __builtin_amdgcn_mfma_f32_16x16x32_bf16(af[m], bfr[n], acc[m][n], 0, 0, 0);
    }
    asm volatile("s_waitcnt vmcnt(0)" ::: "memory");
    __syncthreads();
    cur ^= 1;
  }
#pragma unroll
  for (int m = 0; m < 2; ++m) {
#pragma unroll
    for (int n = 0; n < 4; ++n) {
#pragma unroll
      for (int j = 0; j < 4; ++j) {
        int row = rowBase + wm * 32 + m * 16 + lh * 4 + j;
        int col = colBase + wn * 64 + n * 16 + lr;
        if (col < N) {
          if (BF16_OUT)
            ((u16*)Cv)[(size_t)row * N + col] = f2bf(acc[m][n][j]);
          else
            ((float*)Cv)[(size_t)row * N + col] = acc[m][n][j];
        }
      }
    }
  }
}

// o-proj: 64x128 tiles, grid (16,32)=512 blocks -> 2/CU resident.
__global__ __launch_bounds__(256) void gemm_bt64_f32(const u16* __restrict__ A,
                                                     const u16* __restrict__ B,
                                                     float* __restrict__ C,
                                                     int N, int K) {
  __shared__ __align__(16) u16 As[2 * 4096];
  __shared__ __align__(16) u16 Bs[2 * 8192];
  gemm_core64<false>(As, Bs, A, B, C, N, K, blockIdx.y * 64, blockIdx.x * 128);
}

// qb: 64x128 tiles, grid (24,32)=768 blocks -> exact 3/CU capacity fit.
__global__ __launch_bounds__(256) void gemm_bt64_bf16(const u16* __restrict__ A,
                                                      const u16* __restrict__ B,
                                                      u16* __restrict__ C,
                                                      int N, int K) {
  __shared__ __align__(16) u16 As[2 * 4096];
  __shared__ __align__(16) u16 Bs[2 * 8192];
  gemm_core64<true>(As, Bs, A, B, C, N, K, blockIdx.y * 64, blockIdx.x * 128);
}

// qa|kva (64x128 tiles, 544 GEMM blocks) + overlapped stage-2 conversions
__global__ __launch_bounds__(256) void gemm_qakva_conv(
    const u16* __restrict__ hbf, const u16* __restrict__ wcat, u16* __restrict__ qpre,
    const float* __restrict__ s0, u16* __restrict__ d0, int n0,
    const float* __restrict__ s1, u16* __restrict__ d1, int n1,
    const float* __restrict__ s2, u16* __restrict__ d2, int n2) {
  __shared__ __align__(16) u16 As[2 * 4096];
  __shared__ __align__(16) u16 Bs[2 * 8192];
  const int bx = blockIdx.x;
  if (bx < 544) {
    gemm_core64<true>(As, Bs, hbf, wcat, qpre, NCAT, HIDN, (bx / 17) * 64, (bx % 17) * 128);
  } else {
    const int t = bx - 544;
    const int seg = t >> 6, lb = t & 63;
    const float* s; u16* d; int n4;
    if (seg == 0)      { s = s0; d = d0; n4 = n0; }
    else if (seg == 1) { s = s1; d = d1; n4 = n1; }
    else               { s = s2; d = d2; n4 = n2; }
    conv_span(s, d, n4, lb * 256 + threadIdx.x, 64 * 256);
  }
}

// ---------------- fused RMSNorm (q-latent & k-latent) -----------------------
__global__ __launch_bounds__(256) void rmsnorm2_kernel(const u16* __restrict__ qpre,
                                                       const float* __restrict__ wq,
                                                       u16* __restrict__ qlat,
                                                       const float* __restrict__ wk,
                                                       u16* __restrict__ klat) {
  const int row = blockIdx.x;
  const u16* x; u16* o; const float* w; int L;
  if (blockIdx.y == 0) { x = qpre + (size_t)row * NCAT;       w = wq; o = qlat + (size_t)row * QLR; L = QLR; }
  else                 { x = qpre + (size_t)row * NCAT + QLR; w = wk; o = klat + (size_t)row * KLR; L = KLR; }
  int tid = threadIdx.x;
  float ss = 0.f;
  for (int i = tid; i < L; i += 256) { float v = bf2f(x[i]); ss += v * v; }
#pragma unroll
  for (int off = 32; off > 0; off >>= 1) ss += __shfl_down(ss, off);
  __shared__ float red[4];
  if ((tid & 63) == 0) red[tid >> 6] = ss;
  __syncthreads();
  float tot = red[0] + red[1] + red[2] + red[3];
  float sc = rsqrtf(tot / (float)L + 1e-6f);
  for (int i = tid; i < L; i += 256) o[i] = f2bf(bf2f(x[i]) * sc * w[i]);
}

// ---------------- fused prep: rope(q) | build_k | vtrans --------------------
__global__ __launch_bounds__(256) void prep_kernel(u16* __restrict__ qbuf,
                                                   const u16* __restrict__ kvbuf,
                                                   const u16* __restrict__ qpre,
                                                   const float* __restrict__ cosb,
                                                   const float* __restrict__ sinb,
                                                   u16* __restrict__ Kf,
                                                   u16* __restrict__ Vt) {
  __shared__ u16 sh[32 * 33];
  const int bx = blockIdx.x;
  const int tid = threadIdx.x;
  if (bx < 128) {
    int t = bx * 256 + tid;
    int s = t >> 4, h = t & 15;
    u16* x = qbuf + (size_t)s * (NHEAD * DHEAD) + h * DHEAD + 128;
    float xv[64];
#pragma unroll
    for (int i = 0; i < 64; ++i) xv[i] = bf2f(x[i]);
#pragma unroll
    for (int i = 0; i < 32; ++i) {
      float c = cosb[s * 64 + i], sn = sinb[s * 64 + i];
      x[i]      = f2bf(xv[2 * i] * c - xv[2 * i + 1] * sn);
      x[32 + i] = f2bf(xv[2 * i + 1] * c + xv[2 * i] * sn);
    }
  } else if (bx < 128 + 2048) {
    int s = bx - 128;
    u16* krot = sh;
    if (tid < 32) {
      float c = cosb[s * 64 + tid], sn = sinb[s * 64 + tid];
      float x0 = bf2f(qpre[(size_t)s * NCAT + 2048 + 2 * tid]);
      float x1 = bf2f(qpre[(size_t)s * NCAT + 2048 + 2 * tid + 1]);
      krot[tid]      = f2bf(x0 * c - x1 * sn);
      krot[32 + tid] = f2bf(x1 * c + x0 * sn);
    }
    __syncthreads();
    for (int idx = tid; idx < NHEAD * DHEAD; idx += 256) {
      int h = idx / DHEAD, d = idx % DHEAD;
      u16 v = (d < 128) ? kvbuf[(size_t)s * 4096 + h * 256 + d] : krot[d - 128];
      Kf[((size_t)h * SEQ + s) * DHEAD + d] = v;
    }
  } else {
    int t = bx - 2176;
    int st = t & 63, dt = (t >> 6) & 3, h = t >> 8;
    u16 (*tile)[33] = (u16 (*)[33])sh;
    int tx = tid & 31, ty = tid >> 5;
#pragma unroll
    for (int i = 0; i < 4; ++i) {
      int ss = st * 32 + ty + i * 8;
      tile[ty + i * 8][tx] = kvbuf[(size_t)ss * 4096 + h * 256 + 128 + dt * 32 + tx];
    }
    __syncthreads();
#pragma unroll
    for (int i = 0; i < 4; ++i) {
      int d = dt * 32 + ty + i * 8;
      Vt[((size_t)h * DVAL + d) * SEQ + st * 32 + tx] = tile[tx][ty + i * 8];
    }
  }
}

// ---------------- Causal flash attention, 2-way split-K (R11 pipeline) ------
// + T13 defer-max (THR=8).
__global__ __launch_bounds__(256, 3) void attn_kernel(const u16* __restrict__ qbuf,
                                                      const u16* __restrict__ Kf,
                                                      const u16* __restrict__ Vt,
                                                      u16* __restrict__ attn_out,
                                                      float* __restrict__ Opart,
                                                      float* __restrict__ mlp,
                                                      float scaling) {
  const int bx = blockIdx.x;
  int h, qt, chunk;
  if (bx < 256)      { h = bx & 15;          qt = 31 - (bx >> 4);        chunk = 0; }
  else if (bx < 512) { int t = bx - 256; h = t & 15; qt = t >> 4;        chunk = 0; }
  else               { int t = bx - 512; h = t & 15; qt = 31 - (t >> 4); chunk = 1; }
  const int kt0 = chunk ? 16 : 0;
  const int kte = chunk ? qt : (qt < 15 ? qt : 15);
  const bool direct = (qt < 16);

  const int tid = threadIdx.x;
  const int wid = tid >> 6;
  const int lane = tid & 63;
  const int lr = lane & 15, lh = lane >> 4;

  __shared__ __align__(16) u16 Kl[64 * 192];
  __shared__ __align__(16) u16 Vl[144 * 64];
  __shared__ __align__(16) u16 Plds[4 * 1024];
  u16* Pw = Plds + wid * 1024;
  const int q0 = qt * 64 + wid * 16;

  for (int i = tid; i < 16 * 64; i += 256) Vl[128 * 64 + i] = 0x3F80;

  bf16x8 qf[6];
#pragma unroll
  for (int c = 0; c < 6; ++c) {
    bf16x8 q = *reinterpret_cast<const bf16x8*>(qbuf + (size_t)(q0 + lr) * (NHEAD * DHEAD) +
                                                h * DHEAD + c * 32 + lh * 8);
    bf16x8 o;
#pragma unroll
    for (int e = 0; e < 8; ++e) o[e] = (short)f2bf(bf2f((u16)q[e]) * scaling);
    qf[c] = o;
  }

  int kSrc[6], kDst[6];
#pragma unroll
  for (int i = 0; i < 6; ++i) {
    int slin = i * 256 + tid;
    int row = slin / 24;
    int ck = slin - row * 24;
    int srcck = (ck & 0x18) | ((ck & 7) ^ (row & 7));
    kSrc[i] = row * DHEAD + srcck * 8;
    kDst[i] = slin * 8;
  }
  int vSrc[4], vDst[4];
#pragma unroll
  for (int i = 0; i < 4; ++i) {
    int slin = i * 256 + tid;
    int d = slin >> 3, c = slin & 7;
    vSrc[i] = (c ^ (d & 7)) * 8;
    vDst[i] = slin * 8;
  }
  int qkOff[4][6];
#pragma unroll
  for (int f = 0; f < 4; ++f)
#pragma unroll
    for (int c = 0; c < 6; ++c) {
      int row = f * 16 + lr;
      int ckg = c * 4 + lh;
      int ck = (ckg & 0x18) | ((ckg & 7) ^ (row & 7));
      qkOff[f][c] = row * DHEAD + ck * 8;
    }
  int pvOff[9][2];
#pragma unroll
  for (int f = 0; f < 9; ++f)
#pragma unroll
    for (int kk = 0; kk < 2; ++kk) {
      int d = f * 16 + lr;
      int ckg = kk * 4 + lh;
      pvOff[f][kk] = d * 64 + ((ckg ^ (d & 7)) * 8);
    }
  int paOff[2];
#pragma unroll
  for (int kk = 0; kk < 2; ++kk) paOff[kk] = lr * 64 + (((kk * 4 + lh) ^ (lr & 7)) * 8);
  int pIdx[4][4];
#pragma unroll
  for (int f = 0; f < 4; ++f)
#pragma unroll
    for (int j = 0; j < 4; ++j) {
      int rp = lh * 4 + j;
      int col = f * 16 + lr;
      pIdx[f][j] = rp * 64 + (((col >> 3) ^ (rp & 7)) << 3) + (col & 7);
    }

  auto stageK = [&](int kt) {
    const u16* base = Kf + ((size_t)h * SEQ + kt * 64) * DHEAD;
#pragma unroll
    for (int i = 0; i < 6; ++i)
      __builtin_amdgcn_global_load_lds(
          (const __attribute__((address_space(1))) void*)(base + kSrc[i]),
          (__attribute__((address_space(3))) void*)(Kl + kDst[i]), 16, 0, 0);
  };
  auto stageV = [&](int kt) {
    const u16* base = Vt + (size_t)h * DVAL * SEQ + kt * 64;
#pragma unroll
    for (int i = 0; i < 4; ++i) {
      int d = (i * 256 + tid) >> 3;
      __builtin_amdgcn_global_load_lds(
          (const __attribute__((address_space(1))) void*)(base + (size_t)d * SEQ + vSrc[i]),
          (__attribute__((address_space(3))) void*)(Vl + vDst[i]), 16, 0, 0);
    }
  };

  float m_j[4];
  f32x4 acc[9] = {};
#pragma unroll
  for (int j = 0; j < 4; ++j) m_j[j] = -1e30f;

  stageK(kt0);
  asm volatile("s_waitcnt vmcnt(0)" ::: "memory");
  __syncthreads();

  auto do_iter = [&](int kt, bool maskTile, bool hasNextK) {
    stageV(kt);

    asm volatile("s_waitcnt vmcnt(4)" ::: "memory");
    __builtin_amdgcn_s_barrier();

    f32x4 sf[4] = {};
    __builtin_amdgcn_s_setprio(1);
#pragma unroll
    for (int f = 0; f < 4; ++f)
#pragma unroll
      for (int c = 0; c < 6; ++c) {
        bf16x8 kf = *reinterpret_cast<const bf16x8*>(Kl + qkOff[f][c]);
        sf[f] = __builtin_amdgcn_mfma_f32_16x16x32_bf16(qf[c], kf, sf[f], 0, 0, 0);
      }
    __builtin_amdgcn_s_setprio(0);

    __builtin_amdgcn_s_barrier();
    if (hasNextK) stageK(kt + 1);

    float mx[4];
#pragma unroll
    for (int j = 0; j < 4; ++j) mx[j] = -1e30f;
#pragma unroll
    for (int f = 0; f < 4; ++f)
#pragma unroll
      for (int j = 0; j < 4; ++j) {
        float v = sf[f][j];
        if (maskTile) {
          int kcol = kt * 64 + f * 16 + lr;
          int qrow = q0 + lh * 4 + j;
          if (kcol > qrow) v = -1e30f;
          sf[f][j] = v;
        }
        mx[j] = fmaxf(mx[j], v);
      }
#pragma unroll
    for (int off = 1; off < 16; off <<= 1)
#pragma unroll
      for (int j = 0; j < 4; ++j) mx[j] = fmaxf(mx[j], __shfl_xor(mx[j], off));

    bool need = false;
#pragma unroll
    for (int j = 0; j < 4; ++j) need |= (mx[j] > m_j[j] + 8.0f);
    if (__any(need)) {
      float al[4];
#pragma unroll
      for (int j = 0; j < 4; ++j) {
        float mn = fmaxf(m_j[j], mx[j]);
        al[j] = __expf(m_j[j] - mn);
        m_j[j] = mn;
      }
#pragma unroll
      for (int f = 0; f < 9; ++f)
#pragma unroll
        for (int j = 0; j < 4; ++j) acc[f][j] *= al[j];
    }
#pragma unroll
    for (int f = 0; f < 4; ++f)
#pragma unroll
      for (int j = 0; j < 4; ++j) {
        float p = __expf(sf[f][j] - m_j[j]);
        Pw[pIdx[f][j]] = f2bf(p);
      }

    if (hasNextK) asm volatile("s_waitcnt vmcnt(6)" ::: "memory");
    else          asm volatile("s_waitcnt vmcnt(0)" ::: "memory");
    __builtin_amdgcn_s_barrier();

    __builtin_amdgcn_s_setprio(1);
#pragma unroll
    for (int kk = 0; kk < 2; ++kk) {
      bf16x8 pa = *reinterpret_cast<const bf16x8*>(Pw + paOff[kk]);
#pragma unroll
      for (int f = 0; f < 9; ++f) {
        bf16x8 vb = *reinterpret_cast<const bf16x8*>(Vl + pvOff[f][kk]);
        acc[f] = __builtin_amdgcn_mfma_f32_16x16x32_bf16(pa, vb, acc[f], 0, 0, 0);
      }
    }
    __builtin_amdgcn_s_setprio(0);

    if (hasNextK) __builtin_amdgcn_s_barrier();
  };

  for (int kt = kt0; kt < kte; ++kt) do_iter(kt, false, true);
  do_iter(kte, kte == qt, false);

  if (direct) {
#pragma unroll
    for (int f = 0; f < 8; ++f)
#pragma unroll
      for (int j = 0; j < 4; ++j) {
        int row = q0 + lh * 4 + j;
        float l = acc[8][j];
        attn_out[(size_t)row * (NHEAD * DVAL) + h * DVAL + f * 16 + lr] = f2bf(acc[f][j] / l);
      }
  } else {
    const int pidx = h * 16 + (qt - 16);
    float* Op = Opart + (size_t)(pidx * 2 + chunk) * 8192;
#pragma unroll
    for (int f = 0; f < 8; ++f)
#pragma unroll
      for (int j = 0; j < 4; ++j) {
        int r = wid * 16 + lh * 4 + j;
        Op[r * 128 + f * 16 + lr] = acc[f][j];
      }
    if (lr == 0) {
      float* mlb = mlp + (pidx * 2 + chunk) * 128;
#pragma unroll
      for (int j = 0; j < 4; ++j) {
        int r = wid * 16 + lh * 4 + j;
        mlb[r] = m_j[j];
        mlb[64 + r] = acc[8][j];
      }
    }
  }
}

// ---------------- combine two split-K partials (512 blocks, half each) ------
__global__ __launch_bounds__(256) void attn_combine(const float* __restrict__ Opart,
                                                    const float* __restrict__ mlp,
                                                    u16* __restrict__ attnb) {
  const int b = blockIdx.x;
  const int pid = b >> 1, half = b & 1;
  const int h = pid & 15, q2 = pid >> 4;
  const int pidx = h * 16 + q2;
  const int qt = 16 + q2;
  const float* O0 = Opart + (size_t)(pidx * 2 + 0) * 8192;
  const float* O1 = Opart + (size_t)(pidx * 2 + 1) * 8192;
  const float* ml0 = mlp + (pidx * 2 + 0) * 128;
  const float* ml1 = mlp + (pidx * 2 + 1) * 128;
  __shared__ float w0s[64], w1s[64], iLs[64];
  const int tid = threadIdx.x;
  if (tid < 64) {
    float m0 = ml0[tid], l0 = ml0[64 + tid];
    float m1 = ml1[tid], l1 = ml1[64 + tid];
    float M = fmaxf(m0, m1);
    float a0 = __expf(m0 - M), a1 = __expf(m1 - M);
    w0s[tid] = a0; w1s[tid] = a1;
    iLs[tid] = 1.f / (l0 * a0 + l1 * a1);
  }
  __syncthreads();
  const int base = half * 4096, end = base + 4096;
  for (int idx = base + tid; idx < end; idx += 256) {
    int r = idx >> 7, c = idx & 127;
    float o = (O0[idx] * w0s[r] + O1[idx] * w1s[r]) * iLs[r];
    attnb[(size_t)(qt * 64 + r) * (NHEAD * DVAL) + h * DVAL + c] = f2bf(o);
  }
}

// ---------------- launch ----------------------------------------------------
extern "C" void kernel_launch(void* const* d_in, const int* in_sizes, int n_in,
                              void* d_out, int out_size, void* d_ws, size_t ws_size,
                              hipStream_t stream) {
  const float* hidden   = (const float*)d_in[0];
  const float* cosb     = (const float*)d_in[1];
  const float* sinb     = (const float*)d_in[2];
  const float* w_qa     = (const float*)d_in[3];
  const float* w_qa_ln  = (const float*)d_in[4];
  const float* w_qb     = (const float*)d_in[5];
  const float* w_kva    = (const float*)d_in[6];
  const float* w_kva_ln = (const float*)d_in[7];
  const float* w_kvb    = (const float*)d_in[8];
  const float* w_o      = (const float*)d_in[9];
  float* out = (float*)d_out;

  char* ws = (char*)d_ws;
  size_t off = 0;
  auto alloc = [&](size_t bytes) -> char* {
    char* p = ws + off;
    off = (off + bytes + 255) & ~(size_t)255;
    return p;
  };
  u16* hbf    = (u16*)alloc((size_t)SEQ * HIDN * 2);
  u16* wcat   = (u16*)alloc((size_t)NCAT * HIDN * 2);
  u16* wqbbf  = (u16*)alloc((size_t)(NHEAD * DHEAD) * QLR * 2);
  u16* wkvbbf = (u16*)alloc((size_t)4096 * KLR * 2);
  u16* qpre   = (u16*)alloc((size_t)SEQ * NCAT * 2);
  u16* qlat   = (u16*)alloc((size_t)SEQ * QLR * 2);
  u16* klat   = (u16*)alloc((size_t)SEQ * KLR * 2);
  u16* kvbuf  = (u16*)alloc((size_t)SEQ * 4096 * 2);
  u16* wobf   = (u16*)alloc((size_t)HIDN * HIDN * 2);
  u16* qbuf   = (u16*)alloc((size_t)SEQ * NHEAD * DHEAD * 2);
  u16* Kf     = (u16*)alloc((size_t)NHEAD * SEQ * DHEAD * 2);
  u16* Vt     = (u16*)alloc((size_t)NHEAD * DVAL * SEQ * 2);
  u16* attnb  = (u16*)alloc((size_t)SEQ * NHEAD * DVAL * 2);
  (void)ws_size; (void)n_in; (void)in_sizes; (void)out_size;

  float* Opart = (float*)ws;
  float* mlp   = (float*)(ws + (size_t)512 * 8192 * 4);

  convert3<<<dim3(512, 3), 256, 0, stream>>>(
      hidden, hbf, SEQ * HIDN / 4,
      w_qa, wcat, QLR * HIDN / 4,
      w_kva, wcat + (size_t)QLR * HIDN, 576 * HIDN / 4);

  gemm_qakva_conv<<<dim3(736), 256, 0, stream>>>(
      hbf, wcat, qpre,
      w_qb, wqbbf, NHEAD * DHEAD * QLR / 4,
      w_kvb, wkvbbf, 4096 * KLR / 4,
      w_o, wobf, HIDN * HIDN / 4);

  rmsnorm2_kernel<<<dim3(SEQ, 2), 256, 0, stream>>>(qpre, w_qa_ln, qlat, w_kva_ln, klat);

  gemm_bt64_bf16<<<dim3((NHEAD * DHEAD) / 128, SEQ / 64), 256, 0, stream>>>(qlat, wqbbf, qbuf, NHEAD * DHEAD, QLR);
  gemm_bt<true><<<dim3(4096 / 128, SEQ / 128), 256, 0, stream>>>(klat, wkvbbf, kvbuf, SEQ, 4096, KLR);

  prep_kernel<<<dim3(6272), 256, 0, stream>>>(qbuf, kvbuf, qpre, cosb, sinb, Kf, Vt);

  double Mm = 0.1 * log(40.0) + 1.0;
  float scaling = (float)(pow((double)DHEAD, -0.5) * Mm * Mm);
  attn_kernel<<<dim3(768), 256, 0, stream>>>(qbuf, Kf, Vt, attnb, Opart, mlp, scaling);
  attn_combine<<<dim3(512), 256, 0, stream>>>(Opart, mlp, attnb);

  gemm_bt64_f32<<<dim3(HIDN / 128, SEQ / 64), 256, 0, stream>>>(attnb, wobf, out, HIDN, HIDN);
}